// Round 20
// baseline (3656.270 us; speedup 1.0000x reference)
//
#include <hip/hip_runtime.h>
#include <hip/hip_cooperative_groups.h>

// LSTM: B=64, T=256, IN=512, H=1024 (4H=4096), OUT=512. I/O f32.
// Round-30 = r29 (3545us) with the gate burst re-tiled from 4x16-load
// groups to 8x8-load groups, 4 upfront + rolling reissue (waits
// 24/24/24/24/24/24/16/8):
//   Evidence: pipeline granularity is the one repeat-paying lever
//   (r20 3-deep beat r23 2-deep; r24's 4x8-upfront beat r23 by -85).
//   First exposed wait now covers 8 loads with 24 outstanding behind;
//   later groups retire behind shorter consumes. Same 128 declared
//   staging VGPRs (S0..S3 x {h[4],l[4]}), O-loads fold into S0/S1
//   after their final gate consume (r29's mechanism + its VM_WAIT(0)
//   drain before the arrive — the r28 NaN fix).
//   Consume order ks 0..31 sequential, chains acc0/acc1 unchanged ->
//   bitwise-identical accumulation, absmax must stay 0.0078125.
// Coherence: h stores sc0sc1 -> VM_WAIT(0) -> arrive sync -> flag
// store sc0sc1 -> relaxed poll -> LLC-direct reads. NO fences.
// ws: [0,16K) flags; [64K, +768K) h triple buffer (hi/lo planes).

#define B_   64
#define T_   256
#define IN_  512
#define H_   1024
#define G4_  4096
#define OUT_ 512
#define KTOT 1536   // IN_ + H_

typedef __bf16 bf8v  __attribute__((ext_vector_type(8)));
typedef float  f4v   __attribute__((ext_vector_type(4)));

__device__ __forceinline__ float sigm(float x) { return 1.f / (1.f + __expf(-x)); }
__device__ __forceinline__ float tanh_f(float x) { return 1.f - 2.f / (__expf(2.f * x) + 1.f); }

// LLC-direct 16B load (bypass L1+L2). Tracked manually via vmcnt.
#define GLOAD(dst, p) \
    asm volatile("global_load_dwordx4 %0, %1, off sc0 sc1" \
                 : "=v"(dst) : "v"(p))

#define VM_WAIT(n) do { \
    asm volatile("s_waitcnt vmcnt(" #n ")"); \
    __builtin_amdgcn_sched_barrier(0); \
} while (0)

// Write-through store of one bf16, bypassing L1 (sc0) and L2 (sc1).
__device__ __forceinline__ void store_bf16_wt(__bf16* p, __bf16 v) {
    union { __bf16 b; unsigned short s; } cv; cv.b = v;
    unsigned w = cv.s;
    asm volatile("global_store_short %0, %1, off sc0 sc1"
                 :: "v"(p), "v"(w) : "memory");
}

// x-part of the gate GEMM for timestep tt (r12 order). Plain cached
// loads: x is read-only and, with no invalidates, stays L2-resident.
#define X_PRE(tt, xa0, xa1)                                                   \
    {                                                                         \
        const float* xrow = xs + ((size_t)rowA * T_ + (size_t)(tt)) * IN_ + kq; \
        _Pragma("unroll")                                                     \
        for (int ks = 0; ks < 16; ++ks) {                                     \
            f4v v0 = *(const f4v*)(xrow + ks * 32);                           \
            f4v v1 = *(const f4v*)(xrow + ks * 32 + 4);                       \
            bf8v ah, al;                                                      \
            _Pragma("unroll")                                                 \
            for (int j = 0; j < 4; ++j) {                                     \
                __bf16 h0 = (__bf16)v0[j], h1 = (__bf16)v1[j];                \
                ah[j] = h0;  ah[4 + j] = h1;                                  \
                al[j]     = (__bf16)(v0[j] - (float)h0);                      \
                al[4 + j] = (__bf16)(v1[j] - (float)h1);                      \
            }                                                                 \
            bf8v w = *(const bf8v*)&Wlds[c][ks * 32 + kq];                    \
            xa0 = __builtin_amdgcn_mfma_f32_16x16x32_bf16(ah, w, xa0, 0, 0, 0); \
            xa1 = __builtin_amdgcn_mfma_f32_16x16x32_bf16(al, w, xa1, 0, 0, 0); \
        }                                                                     \
    }

// issue one 4-iter group of gate h loads (8 LLC-direct loads)
#define GISSUE4(Hreg, Lreg, kb)                                               \
    _Pragma("unroll")                                                         \
    for (int i = 0; i < 4; ++i) {                                             \
        GLOAD(Hreg[i], hh + ((kb) + i) * 32);                                 \
        GLOAD(Lreg[i], hl + ((kb) + i) * 32);                                 \
    }

// consume one 4-iter group (order identical to r12's ks sweep)
#define GCONSUME4(Hreg, Lreg, kb)                                             \
    _Pragma("unroll")                                                         \
    for (int i = 0; i < 4; ++i) {                                             \
        bf8v w = *(const bf8v*)&Wlds[c][IN_ + ((kb) + i) * 32 + kq];          \
        acc0 = __builtin_amdgcn_mfma_f32_16x16x32_bf16(                       \
            __builtin_bit_cast(bf8v, Hreg[i]), w, acc0, 0, 0, 0);             \
        acc1 = __builtin_amdgcn_mfma_f32_16x16x32_bf16(                       \
            __builtin_bit_cast(bf8v, Lreg[i]), w, acc1, 0, 0, 0);             \
    }

__global__ void __launch_bounds__(256, 1)
lstm_fused(const float* __restrict__ xs, const float* __restrict__ Wi,
           const float* __restrict__ Wh, const float* __restrict__ bias,
           const float* __restrict__ Wo, const float* __restrict__ bo,
           float* __restrict__ out, __bf16* __restrict__ hws,
           unsigned* __restrict__ flags)
{
    __shared__ __bf16 Wlds[16][KTOT + 8];   // 49408 B (bf16-rounded weights)
    __shared__ float  gbuf[64][17];         // 4352 B
    __shared__ float  obuf[4][16][17];      // 4352 B   (total 58112 B)

    const int tid = threadIdx.x;
    const int blk = blockIdx.x;       // 0..255
    const int j0  = blk * 4;
    const int ob0 = (blk >> 5) * 8;   // out-proj batch group (8 batches)
    const int oc0 = (blk & 31) * 16;  // out-proj col group (16 cols)

    // Stage resident gate-weight slab (f32 -> bf16)
    for (int idx = tid; idx < 16 * KTOT; idx += 256) {
        int k = idx >> 4, c = idx & 15;
        int gc = (c >> 2) * H_ + j0 + (c & 3);
        float w = (k < IN_) ? Wi[(size_t)k * G4_ + gc]
                            : Wh[(size_t)(k - IN_) * G4_ + gc];
        Wlds[c][k] = (__bf16)w;
    }
    __syncthreads();

    const int lane = tid & 63;
    const int wave = tid >> 6;
    const int c    = lane & 15;
    const int quad = lane >> 4;
    const int rowA = wave * 16 + c;   // batch row for gate A-frags
    const int kq   = quad * 8;

    const float biasv = bias[(c >> 2) * H_ + j0 + (c & 3)];

    // Hoist step-invariant Wo fragments into registers (f32 -> bf16)
    bf8v wof[8];
    #pragma unroll
    for (int kk = 0; kk < 8; ++kk) {
        int kbase = wave * 256 + kk * 32 + kq;
        #pragma unroll
        for (int j = 0; j < 8; ++j)
            wof[kk][j] = (__bf16)Wo[(size_t)(kbase + j) * OUT_ + oc0 + c];
    }

    // recurrent cell state: thread owns (batch = tid>>2, j = j0 + (tid&3))
    float c_reg = 0.f;
    const int bb = tid >> 2;
    const int jo = tid & 3;

    // x partial accumulators for the upcoming step (prologue: t=0)
    f4v xacc0 = {0.f, 0.f, 0.f, 0.f};
    f4v xacc1 = {0.f, 0.f, 0.f, 0.f};
    X_PRE(0, xacc0, xacc1);

    const size_t bufsz = (size_t)2 * B_ * H_;   // bf16 per buffer (hi+lo planes)

    for (int t = 0; t < T_; ++t) {
        asm volatile("" ::: "memory");   // pin loads below the barrier exit
        const int br = (t + 2) % 3;   // buffer holding h_{t-1}
        const int bw = t % 3;         // buffer for h_t
        const __bf16* hhi_p = hws + (size_t)br * bufsz;
        const __bf16* hlo_p = hhi_p + B_ * H_;
        __bf16* hhi_c = hws + (size_t)bw * bufsz;
        __bf16* hlo_c = hhi_c + B_ * H_;

        // staging: 4 slots x {h[4], l[4]} = 128 declared VGPRs.
        // After their final gate consume, S0 carries O-hi and S1 O-lo
        // into shadow-1.
        f4v S0h[4], S0l[4], S1h[4], S1l[4];
        f4v S2h[4], S2l[4], S3h[4], S3l[4];

        // ---- phase A: gate MFMA for step t (x part precomputed);
        //      8x8-load pipeline, 4 groups upfront, rolling reissue ----
        f4v acc0 = xacc0;   // hi-product chain
        f4v acc1 = xacc1;   // lo-product chain
        if (t > 0) {
            const __bf16* hh = hhi_p + (size_t)rowA * H_ + kq;
            const __bf16* hl = hlo_p + (size_t)rowA * H_ + kq;
            const __bf16* orh = hhi_p + (size_t)(ob0 + c) * H_;
            const __bf16* orl = hlo_p + (size_t)(ob0 + c) * H_;
            GISSUE4(S0h, S0l, 0);     // g0 [8]
            GISSUE4(S1h, S1l, 4);     // g1 [16]
            GISSUE4(S2h, S2l, 8);     // g2 [24]
            GISSUE4(S3h, S3l, 12);    // g3 [32]
            VM_WAIT(24);              // g0 retired
            GCONSUME4(S0h, S0l, 0);
            GISSUE4(S0h, S0l, 16);    // g4 [32]
            VM_WAIT(24);              // g1 retired
            GCONSUME4(S1h, S1l, 4);
            GISSUE4(S1h, S1l, 20);    // g5 [32]
            VM_WAIT(24);              // g2 retired
            GCONSUME4(S2h, S2l, 8);
            GISSUE4(S2h, S2l, 24);    // g6 [32]
            VM_WAIT(24);              // g3 retired
            GCONSUME4(S3h, S3l, 12);
            GISSUE4(S3h, S3l, 28);    // g7 [32]
            VM_WAIT(24);              // g4 retired
            GCONSUME4(S0h, S0l, 16);
            // ---- fold: O-hi loads into freed S0 (Oh[kk]: kk<4 -> S0h, else S0l)
            #pragma unroll
            for (int kk = 0; kk < 4; ++kk) {
                S0h[kk] = (f4v){0.f, 0.f, 0.f, 0.f};
                S0l[kk] = (f4v){0.f, 0.f, 0.f, 0.f};
            }
            if (c < 8) {
                #pragma unroll
                for (int kk = 0; kk < 8; ++kk) {
                    f4v* dst = (kk < 4) ? &S0h[kk] : &S0l[kk - 4];
                    GLOAD(*dst, orh + wave * 256 + kk * 32 + kq);
                }
            }                         // [32]
            VM_WAIT(24);              // g5 retired
            GCONSUME4(S1h, S1l, 20);
            // ---- fold: O-lo loads into freed S1 ----
            #pragma unroll
            for (int kk = 0; kk < 4; ++kk) {
                S1h[kk] = (f4v){0.f, 0.f, 0.f, 0.f};
                S1l[kk] = (f4v){0.f, 0.f, 0.f, 0.f};
            }
            if (c < 8) {
                #pragma unroll
                for (int kk = 0; kk < 8; ++kk) {
                    f4v* dst = (kk < 4) ? &S1h[kk] : &S1l[kk - 4];
                    GLOAD(*dst, orl + wave * 256 + kk * 32 + kq);
                }
            }                         // [32]
            VM_WAIT(16);              // g6 retired
            GCONSUME4(S2h, S2l, 24);
            VM_WAIT(8);               // g7 retired (O stays in flight)
            GCONSUME4(S3h, S3l, 28);
        }
        f4v acc = acc0 + acc1;
        #pragma unroll
        for (int r = 0; r < 4; ++r)
            gbuf[wave * 16 + quad * 4 + r][c] = acc[r] + biasv;  // C: col=c, row=quad*4+r
        // NO __syncthreads: phase B reads only THIS wave's gbuf rows
        // (bb = tid>>2 in [16w, 16w+16) for tid in wave w).
        asm volatile("s_waitcnt lgkmcnt(0)");
        __builtin_amdgcn_sched_barrier(0);

        // ---- phase B: elementwise cell update, write h_t (hi+lo, write-through) ----
        {
            float gi = gbuf[bb][jo];
            float gf = gbuf[bb][4 + jo];
            float gg = gbuf[bb][8 + jo];
            float go = gbuf[bb][12 + jo];
            c_reg = sigm(gf) * c_reg + sigm(gi) * tanh_f(gg);
            float hn = sigm(go) * tanh_f(c_reg);
            __bf16 hh2 = (__bf16)hn;
            store_bf16_wt(&hhi_c[(size_t)bb * H_ + j0 + jo], hh2);
            store_bf16_wt(&hlo_c[(size_t)bb * H_ + j0 + jo], (__bf16)(hn - (float)hh2));
        }

        // ---- drain O loads AND h stores before the arrive (the r29 fix:
        // inline-asm vmem ops are invisible to __syncthreads' lowering).
        // O retired mostly under g6/g7-consume + phase B -> near-free.
        VM_WAIT(0);

        // ==== arrive; shadow work; poll (NO fence anywhere) ====
        __syncthreads();
        const unsigned tgt = (unsigned)(t + 1);
        if (tid == 0) {
            unsigned* p = &flags[blk * 16];
            asm volatile("global_store_dword %0, %1, off sc0 sc1"
                         :: "v"(p), "v"(tgt) : "memory");
        }

        // ---- shadow 1: out-proj MFMAs for step t-1 — fragments in S0
        // (O-hi) and S1 (O-lo), drained by VM_WAIT(0): NO loads, NO wait.
        // Race-free: buf br next overwritten at step t+2's phase B, ordered
        // after barrier(t+1), which needs our flag(t+1), set above.
        if (t > 0) {
            f4v oac = {0.f, 0.f, 0.f, 0.f};
            #pragma unroll
            for (int kk = 0; kk < 8; ++kk) {
                f4v oh = (kk < 4) ? S0h[kk] : S0l[kk - 4];
                f4v ol = (kk < 4) ? S1h[kk] : S1l[kk - 4];
                oac = __builtin_amdgcn_mfma_f32_16x16x32_bf16(
                    __builtin_bit_cast(bf8v, oh), wof[kk], oac, 0, 0, 0);
                oac = __builtin_amdgcn_mfma_f32_16x16x32_bf16(
                    __builtin_bit_cast(bf8v, ol), wof[kk], oac, 0, 0, 0);
            }
            #pragma unroll
            for (int r = 0; r < 4; ++r)
                obuf[wave][quad * 4 + r][c] = oac[r];
        }
        __syncthreads();   // obuf visible to reducers (intra-block)

        // ---- shadow 2: reduce out-proj partials, store out[:, t-1, :] ----
        if (t > 0 && tid < 128) {
            int m = tid >> 4, cc = tid & 15;
            float v = obuf[0][m][cc] + obuf[1][m][cc] + obuf[2][m][cc] + obuf[3][m][cc]
                    + bo[oc0 + cc];
            out[(((size_t)(ob0 + m)) * T_ + (t - 1)) * OUT_ + oc0 + cc] = v;
        }

        // ---- shadow 3: x-part of step t+1 (no dependence on h_t) ----
        xacc0 = (f4v){0.f, 0.f, 0.f, 0.f};
        xacc1 = (f4v){0.f, 0.f, 0.f, 0.f};
        if (t + 1 < T_) {
            X_PRE(t + 1, xacc0, xacc1);
        }
        asm volatile("" ::: "memory");   // pin shadow loads above the poll

        // ---- wait (relaxed poll; no fence: h readers are LLC-direct) ----
        if (tid < 64) {
            const int lane2 = tid;
            for (;;) {
                unsigned m0 = __hip_atomic_load(&flags[(lane2 * 4 + 0) * 16],
                                                __ATOMIC_RELAXED, __HIP_MEMORY_SCOPE_AGENT);
                unsigned m1 = __hip_atomic_load(&flags[(lane2 * 4 + 1) * 16],
                                                __ATOMIC_RELAXED, __HIP_MEMORY_SCOPE_AGENT);
                unsigned m2 = __hip_atomic_load(&flags[(lane2 * 4 + 2) * 16],
                                                __ATOMIC_RELAXED, __HIP_MEMORY_SCOPE_AGENT);
                unsigned m3 = __hip_atomic_load(&flags[(lane2 * 4 + 3) * 16],
                                                __ATOMIC_RELAXED, __HIP_MEMORY_SCOPE_AGENT);
                bool ok = (m0 >= tgt) & (m1 >= tgt) & (m2 >= tgt) & (m3 >= tgt);
                if (__all(ok)) break;
                __builtin_amdgcn_s_sleep(1);
            }
        }
        __syncthreads();
    }

    // ---- epilogue: out-proj for t = T-1 (h_{T-1} in buf (T-1)%3 = 0) ----
    {
        const __bf16* hhi_l = hws;            // buf 0
        const __bf16* hlo_l = hws + B_ * H_;
        f4v Oh[8], Ol[8];
        #pragma unroll
        for (int kk = 0; kk < 8; ++kk) {
            Oh[kk] = (f4v){0.f, 0.f, 0.f, 0.f};
            Ol[kk] = (f4v){0.f, 0.f, 0.f, 0.f};
        }
        const __bf16* orh = hhi_l + (size_t)(ob0 + c) * H_;
        const __bf16* orl = hlo_l + (size_t)(ob0 + c) * H_;
        if (c < 8) {
            #pragma unroll
            for (int kk = 0; kk < 8; ++kk) {
                GLOAD(Oh[kk], orh + wave * 256 + kk * 32 + kq);
                GLOAD(Ol[kk], orl + wave * 256 + kk * 32 + kq);
            }
        }
        VM_WAIT(0);
        f4v oac = {0.f, 0.f, 0.f, 0.f};
        #pragma unroll
        for (int kk = 0; kk < 8; ++kk) {
            oac = __builtin_amdgcn_mfma_f32_16x16x32_bf16(
                __builtin_bit_cast(bf8v, Oh[kk]), wof[kk], oac, 0, 0, 0);
            oac = __builtin_amdgcn_mfma_f32_16x16x32_bf16(
                __builtin_bit_cast(bf8v, Ol[kk]), wof[kk], oac, 0, 0, 0);
        }
        #pragma unroll
        for (int r = 0; r < 4; ++r)
            obuf[wave][quad * 4 + r][c] = oac[r];
        __syncthreads();
        if (tid < 128) {
            int m = tid >> 4, cc = tid & 15;
            float v = obuf[0][m][cc] + obuf[1][m][cc] + obuf[2][m][cc] + obuf[3][m][cc]
                    + bo[oc0 + cc];
            out[(((size_t)(ob0 + m)) * T_ + (T_ - 1)) * OUT_ + oc0 + cc] = v;
        }
    }
}

extern "C" void kernel_launch(void* const* d_in, const int* in_sizes, int n_in,
                              void* d_out, int out_size, void* d_ws, size_t ws_size,
                              hipStream_t stream) {
    const float* xs = (const float*)d_in[0];
    const float* Wi = (const float*)d_in[1];
    const float* Wh = (const float*)d_in[2];
    const float* b  = (const float*)d_in[3];
    const float* Wo = (const float*)d_in[4];
    const float* bo = (const float*)d_in[5];
    float* out = (float*)d_out;

    // ws layout: [0,16K) flag vector (256 x 64B-padded, zeroed);
    //            [64K, +768K) h TRIPLE buffer (hi/lo planes, bf16)
    unsigned* flags = (unsigned*)d_ws;         // flags[i*16], i = 0..255
    __bf16*   hws   = (__bf16*)((char*)d_ws + 65536);

    hipMemsetAsync(d_ws, 0, 32768, stream);    // reset flags (graph-capture safe)

    void* args[] = {(void*)&xs, (void*)&Wi, (void*)&Wh, (void*)&b,
                    (void*)&Wo, (void*)&bo, (void*)&out, (void*)&hws,
                    (void*)&flags};
    hipLaunchCooperativeKernel((void*)lstm_fused, dim3(256), dim3(256), args, 0, stream);
}

// Round 21
// 3628.396 us; speedup vs baseline: 1.0077x; 1.0077x over previous
//
#include <hip/hip_runtime.h>
#include <hip/hip_cooperative_groups.h>

// LSTM: B=64, T=256, IN=512, H=1024 (4H=4096), OUT=512. I/O f32.
// Round-31 = r29 VERBATIM (3545us session champion). r30's finer
// 8x8-group pipeline REGRESSED (+111us: 2x the VM_WAITs, half the
// per-burst coalescing) -> granularity family is bracketed and r29's
// 4x16-group 2-deep rotation is its optimum. Reverting.
//   Champion structure: bf16 hi/lo datapath, LLC-direct h (asm
//   global_load/store sc0 sc1, NO fences anywhere), flag-vector
//   barrier with relaxed agent poll, triple h buffer, A2 out-proj
//   loads folded into the gate burst + explicit VM_WAIT(0) drain
//   before the arrive (inline-asm vmem is invisible to __syncthreads
//   lowering — the r28 NaN lesson), shadowed A2-MFMA/B2/x-pre.
//   Session: 5852 -> 3545us (1.65x). Remaining step time is the
//   irreducible serial chain: gate LLC RTT + consume + cell update +
//   publish drain + flag propagate + detect + skew (~13.9us/step);
//   HBM 2.9%, MfmaUtil 5.4% — latency-bound by the T=256 recurrence,
//   not a hardware roofline.
// ws: [0,16K) flags; [64K, +768K) h triple buffer (hi/lo planes).

#define B_   64
#define T_   256
#define IN_  512
#define H_   1024
#define G4_  4096
#define OUT_ 512
#define KTOT 1536   // IN_ + H_

typedef __bf16 bf8v  __attribute__((ext_vector_type(8)));
typedef float  f4v   __attribute__((ext_vector_type(4)));

__device__ __forceinline__ float sigm(float x) { return 1.f / (1.f + __expf(-x)); }
__device__ __forceinline__ float tanh_f(float x) { return 1.f - 2.f / (__expf(2.f * x) + 1.f); }

// LLC-direct 16B load (bypass L1+L2). Tracked manually via vmcnt.
#define GLOAD(dst, p) \
    asm volatile("global_load_dwordx4 %0, %1, off sc0 sc1" \
                 : "=v"(dst) : "v"(p))

#define VM_WAIT(n) do { \
    asm volatile("s_waitcnt vmcnt(" #n ")"); \
    __builtin_amdgcn_sched_barrier(0); \
} while (0)

// Write-through store of one bf16, bypassing L1 (sc0) and L2 (sc1).
__device__ __forceinline__ void store_bf16_wt(__bf16* p, __bf16 v) {
    union { __bf16 b; unsigned short s; } cv; cv.b = v;
    unsigned w = cv.s;
    asm volatile("global_store_short %0, %1, off sc0 sc1"
                 :: "v"(p), "v"(w) : "memory");
}

// x-part of the gate GEMM for timestep tt (r12 order). Plain cached
// loads: x is read-only and, with no invalidates, stays L2-resident.
#define X_PRE(tt, xa0, xa1)                                                   \
    {                                                                         \
        const float* xrow = xs + ((size_t)rowA * T_ + (size_t)(tt)) * IN_ + kq; \
        _Pragma("unroll")                                                     \
        for (int ks = 0; ks < 16; ++ks) {                                     \
            f4v v0 = *(const f4v*)(xrow + ks * 32);                           \
            f4v v1 = *(const f4v*)(xrow + ks * 32 + 4);                       \
            bf8v ah, al;                                                      \
            _Pragma("unroll")                                                 \
            for (int j = 0; j < 4; ++j) {                                     \
                __bf16 h0 = (__bf16)v0[j], h1 = (__bf16)v1[j];                \
                ah[j] = h0;  ah[4 + j] = h1;                                  \
                al[j]     = (__bf16)(v0[j] - (float)h0);                      \
                al[4 + j] = (__bf16)(v1[j] - (float)h1);                      \
            }                                                                 \
            bf8v w = *(const bf8v*)&Wlds[c][ks * 32 + kq];                    \
            xa0 = __builtin_amdgcn_mfma_f32_16x16x32_bf16(ah, w, xa0, 0, 0, 0); \
            xa1 = __builtin_amdgcn_mfma_f32_16x16x32_bf16(al, w, xa1, 0, 0, 0); \
        }                                                                     \
    }

// issue one 8-iter group of gate h loads (16 LLC-direct loads)
#define GISSUE(Hreg, Lreg, kb)                                                \
    _Pragma("unroll")                                                         \
    for (int i = 0; i < 8; ++i) {                                             \
        GLOAD(Hreg[i], hh + ((kb) + i) * 32);                                 \
        GLOAD(Lreg[i], hl + ((kb) + i) * 32);                                 \
    }

// consume one 8-iter group (order identical to r12's ks sweep)
#define GCONSUME(Hreg, Lreg, kb)                                              \
    _Pragma("unroll")                                                         \
    for (int i = 0; i < 8; ++i) {                                             \
        bf8v w = *(const bf8v*)&Wlds[c][IN_ + ((kb) + i) * 32 + kq];          \
        acc0 = __builtin_amdgcn_mfma_f32_16x16x32_bf16(                       \
            __builtin_bit_cast(bf8v, Hreg[i]), w, acc0, 0, 0, 0);             \
        acc1 = __builtin_amdgcn_mfma_f32_16x16x32_bf16(                       \
            __builtin_bit_cast(bf8v, Lreg[i]), w, acc1, 0, 0, 0);             \
    }

__global__ void __launch_bounds__(256, 1)
lstm_fused(const float* __restrict__ xs, const float* __restrict__ Wi,
           const float* __restrict__ Wh, const float* __restrict__ bias,
           const float* __restrict__ Wo, const float* __restrict__ bo,
           float* __restrict__ out, __bf16* __restrict__ hws,
           unsigned* __restrict__ flags)
{
    __shared__ __bf16 Wlds[16][KTOT + 8];   // 49408 B (bf16-rounded weights)
    __shared__ float  gbuf[64][17];         // 4352 B
    __shared__ float  obuf[4][16][17];      // 4352 B   (total 58112 B)

    const int tid = threadIdx.x;
    const int blk = blockIdx.x;       // 0..255
    const int j0  = blk * 4;
    const int ob0 = (blk >> 5) * 8;   // out-proj batch group (8 batches)
    const int oc0 = (blk & 31) * 16;  // out-proj col group (16 cols)

    // Stage resident gate-weight slab (f32 -> bf16)
    for (int idx = tid; idx < 16 * KTOT; idx += 256) {
        int k = idx >> 4, c = idx & 15;
        int gc = (c >> 2) * H_ + j0 + (c & 3);
        float w = (k < IN_) ? Wi[(size_t)k * G4_ + gc]
                            : Wh[(size_t)(k - IN_) * G4_ + gc];
        Wlds[c][k] = (__bf16)w;
    }
    __syncthreads();

    const int lane = tid & 63;
    const int wave = tid >> 6;
    const int c    = lane & 15;
    const int quad = lane >> 4;
    const int rowA = wave * 16 + c;   // batch row for gate A-frags
    const int kq   = quad * 8;

    const float biasv = bias[(c >> 2) * H_ + j0 + (c & 3)];

    // Hoist step-invariant Wo fragments into registers (f32 -> bf16)
    bf8v wof[8];
    #pragma unroll
    for (int kk = 0; kk < 8; ++kk) {
        int kbase = wave * 256 + kk * 32 + kq;
        #pragma unroll
        for (int j = 0; j < 8; ++j)
            wof[kk][j] = (__bf16)Wo[(size_t)(kbase + j) * OUT_ + oc0 + c];
    }

    // recurrent cell state: thread owns (batch = tid>>2, j = j0 + (tid&3))
    float c_reg = 0.f;
    const int bb = tid >> 2;
    const int jo = tid & 3;

    // x partial accumulators for the upcoming step (prologue: t=0)
    f4v xacc0 = {0.f, 0.f, 0.f, 0.f};
    f4v xacc1 = {0.f, 0.f, 0.f, 0.f};
    X_PRE(0, xacc0, xacc1);

    const size_t bufsz = (size_t)2 * B_ * H_;   // bf16 per buffer (hi+lo planes)

    for (int t = 0; t < T_; ++t) {
        asm volatile("" ::: "memory");   // pin loads below the barrier exit
        const int br = (t + 2) % 3;   // buffer holding h_{t-1}
        const int bw = t % 3;         // buffer for h_t
        const __bf16* hhi_p = hws + (size_t)br * bufsz;
        const __bf16* hlo_p = hhi_p + B_ * H_;
        __bf16* hhi_c = hws + (size_t)bw * bufsz;
        __bf16* hlo_c = hhi_c + B_ * H_;

        // staging (exactly 128 declared VGPRs; Ah0/Al0 double as the
        // A2 fragment carrier from phase A into shadow-1)
        f4v Ah0[8], Al0[8], Ah1[8], Al1[8];

        // ---- phase A: gate MFMA for step t (x part precomputed);
        //      A2's loads fold into the tail of the burst ----
        f4v acc0 = xacc0;   // hi-product chain
        f4v acc1 = xacc1;   // lo-product chain
        if (t > 0) {
            const __bf16* hh = hhi_p + (size_t)rowA * H_ + kq;
            const __bf16* hl = hlo_p + (size_t)rowA * H_ + kq;
            const __bf16* orh = hhi_p + (size_t)(ob0 + c) * H_;
            const __bf16* orl = hlo_p + (size_t)(ob0 + c) * H_;
            GISSUE(Ah0, Al0, 0);      // G0   [16]
            GISSUE(Ah1, Al1, 8);      // G1   [32]
            VM_WAIT(16);              // G0 retired
            GCONSUME(Ah0, Al0, 0);
            GISSUE(Ah0, Al0, 16);     // G2 into G0's registers [32]
            VM_WAIT(16);              // G1 retired
            GCONSUME(Ah1, Al1, 8);
            GISSUE(Ah1, Al1, 24);     // G3 into G1's registers [32]
            VM_WAIT(16);              // G2 retired
            GCONSUME(Ah0, Al0, 16);
            // ---- fold: A2 loads into freed Ah0/Al0 [G3=16 + O=16] ----
            #pragma unroll
            for (int kk = 0; kk < 8; ++kk) {
                Ah0[kk] = (f4v){0.f, 0.f, 0.f, 0.f};
                Al0[kk] = (f4v){0.f, 0.f, 0.f, 0.f};
            }
            if (c < 8) {   // A rows 8..15 zero (8 batches per tile)
                #pragma unroll
                for (int kk = 0; kk < 8; ++kk) {
                    GLOAD(Ah0[kk], orh + wave * 256 + kk * 32 + kq);
                    GLOAD(Al0[kk], orl + wave * 256 + kk * 32 + kq);
                }
            }
            VM_WAIT(16);              // G3 retired (O stays in flight)
            GCONSUME(Ah1, Al1, 24);
        }
        f4v acc = acc0 + acc1;
        #pragma unroll
        for (int r = 0; r < 4; ++r)
            gbuf[wave * 16 + quad * 4 + r][c] = acc[r] + biasv;  // C: col=c, row=quad*4+r
        // NO __syncthreads: phase B reads only THIS wave's gbuf rows
        // (bb = tid>>2 in [16w, 16w+16) for tid in wave w).
        asm volatile("s_waitcnt lgkmcnt(0)");
        __builtin_amdgcn_sched_barrier(0);

        // ---- phase B: elementwise cell update, write h_t (hi+lo, write-through) ----
        {
            float gi = gbuf[bb][jo];
            float gf = gbuf[bb][4 + jo];
            float gg = gbuf[bb][8 + jo];
            float go = gbuf[bb][12 + jo];
            c_reg = sigm(gf) * c_reg + sigm(gi) * tanh_f(gg);
            float hn = sigm(go) * tanh_f(c_reg);
            __bf16 hh2 = (__bf16)hn;
            store_bf16_wt(&hhi_c[(size_t)bb * H_ + j0 + jo], hh2);
            store_bf16_wt(&hlo_c[(size_t)bb * H_ + j0 + jo], (__bf16)(hn - (float)hh2));
        }

        // ---- drain O loads AND h stores before the arrive (r29 fix:
        // inline-asm vmem ops are invisible to __syncthreads' barrier
        // lowering -> r28's NaN. O retired mostly under phase B already,
        // so this wait is near-free; it also makes h-store -> flag
        // ordering architecturally sound.)
        VM_WAIT(0);

        // ==== arrive; shadow work; poll (NO fence anywhere) ====
        __syncthreads();
        const unsigned tgt = (unsigned)(t + 1);
        if (tid == 0) {
            unsigned* p = &flags[blk * 16];
            asm volatile("global_store_dword %0, %1, off sc0 sc1"
                         :: "v"(p), "v"(tgt) : "memory");
        }

        // ---- shadow 1: out-proj MFMAs for step t-1 — fragments already in
        // Ah0/Al0 (loaded in phase A, drained by VM_WAIT(0)): NO loads,
        // NO wait. Race-free: buf br next overwritten at step t+2's phase B,
        // ordered after barrier(t+1), which needs our flag(t+1), set above.
        if (t > 0) {
            f4v oac = {0.f, 0.f, 0.f, 0.f};
            #pragma unroll
            for (int kk = 0; kk < 8; ++kk) {
                oac = __builtin_amdgcn_mfma_f32_16x16x32_bf16(
                    __builtin_bit_cast(bf8v, Ah0[kk]), wof[kk], oac, 0, 0, 0);
                oac = __builtin_amdgcn_mfma_f32_16x16x32_bf16(
                    __builtin_bit_cast(bf8v, Al0[kk]), wof[kk], oac, 0, 0, 0);
            }
            #pragma unroll
            for (int r = 0; r < 4; ++r)
                obuf[wave][quad * 4 + r][c] = oac[r];
        }
        __syncthreads();   // obuf visible to reducers (intra-block)

        // ---- shadow 2: reduce out-proj partials, store out[:, t-1, :] ----
        if (t > 0 && tid < 128) {
            int m = tid >> 4, cc = tid & 15;
            float v = obuf[0][m][cc] + obuf[1][m][cc] + obuf[2][m][cc] + obuf[3][m][cc]
                    + bo[oc0 + cc];
            out[(((size_t)(ob0 + m)) * T_ + (t - 1)) * OUT_ + oc0 + cc] = v;
        }

        // ---- shadow 3: x-part of step t+1 (no dependence on h_t) ----
        xacc0 = (f4v){0.f, 0.f, 0.f, 0.f};
        xacc1 = (f4v){0.f, 0.f, 0.f, 0.f};
        if (t + 1 < T_) {
            X_PRE(t + 1, xacc0, xacc1);
        }
        asm volatile("" ::: "memory");   // pin shadow loads above the poll

        // ---- wait (relaxed poll; no fence: h readers are LLC-direct) ----
        if (tid < 64) {
            const int lane2 = tid;
            for (;;) {
                unsigned m0 = __hip_atomic_load(&flags[(lane2 * 4 + 0) * 16],
                                                __ATOMIC_RELAXED, __HIP_MEMORY_SCOPE_AGENT);
                unsigned m1 = __hip_atomic_load(&flags[(lane2 * 4 + 1) * 16],
                                                __ATOMIC_RELAXED, __HIP_MEMORY_SCOPE_AGENT);
                unsigned m2 = __hip_atomic_load(&flags[(lane2 * 4 + 2) * 16],
                                                __ATOMIC_RELAXED, __HIP_MEMORY_SCOPE_AGENT);
                unsigned m3 = __hip_atomic_load(&flags[(lane2 * 4 + 3) * 16],
                                                __ATOMIC_RELAXED, __HIP_MEMORY_SCOPE_AGENT);
                bool ok = (m0 >= tgt) & (m1 >= tgt) & (m2 >= tgt) & (m3 >= tgt);
                if (__all(ok)) break;
                __builtin_amdgcn_s_sleep(1);
            }
        }
        __syncthreads();
    }

    // ---- epilogue: out-proj for t = T-1 (h_{T-1} in buf (T-1)%3 = 0) ----
    {
        const __bf16* hhi_l = hws;            // buf 0
        const __bf16* hlo_l = hws + B_ * H_;
        f4v Oh[8], Ol[8];
        #pragma unroll
        for (int kk = 0; kk < 8; ++kk) {
            Oh[kk] = (f4v){0.f, 0.f, 0.f, 0.f};
            Ol[kk] = (f4v){0.f, 0.f, 0.f, 0.f};
        }
        const __bf16* orh = hhi_l + (size_t)(ob0 + c) * H_;
        const __bf16* orl = hlo_l + (size_t)(ob0 + c) * H_;
        if (c < 8) {
            #pragma unroll
            for (int kk = 0; kk < 8; ++kk) {
                GLOAD(Oh[kk], orh + wave * 256 + kk * 32 + kq);
                GLOAD(Ol[kk], orl + wave * 256 + kk * 32 + kq);
            }
        }
        VM_WAIT(0);
        f4v oac = {0.f, 0.f, 0.f, 0.f};
        #pragma unroll
        for (int kk = 0; kk < 8; ++kk) {
            oac = __builtin_amdgcn_mfma_f32_16x16x32_bf16(
                __builtin_bit_cast(bf8v, Oh[kk]), wof[kk], oac, 0, 0, 0);
            oac = __builtin_amdgcn_mfma_f32_16x16x32_bf16(
                __builtin_bit_cast(bf8v, Ol[kk]), wof[kk], oac, 0, 0, 0);
        }
        #pragma unroll
        for (int r = 0; r < 4; ++r)
            obuf[wave][quad * 4 + r][c] = oac[r];
        __syncthreads();
        if (tid < 128) {
            int m = tid >> 4, cc = tid & 15;
            float v = obuf[0][m][cc] + obuf[1][m][cc] + obuf[2][m][cc] + obuf[3][m][cc]
                    + bo[oc0 + cc];
            out[(((size_t)(ob0 + m)) * T_ + (T_ - 1)) * OUT_ + oc0 + cc] = v;
        }
    }
}

extern "C" void kernel_launch(void* const* d_in, const int* in_sizes, int n_in,
                              void* d_out, int out_size, void* d_ws, size_t ws_size,
                              hipStream_t stream) {
    const float* xs = (const float*)d_in[0];
    const float* Wi = (const float*)d_in[1];
    const float* Wh = (const float*)d_in[2];
    const float* b  = (const float*)d_in[3];
    const float* Wo = (const float*)d_in[4];
    const float* bo = (const float*)d_in[5];
    float* out = (float*)d_out;

    // ws layout: [0,16K) flag vector (256 x 64B-padded, zeroed);
    //            [64K, +768K) h TRIPLE buffer (hi/lo planes, bf16)
    unsigned* flags = (unsigned*)d_ws;         // flags[i*16], i = 0..255
    __bf16*   hws   = (__bf16*)((char*)d_ws + 65536);

    hipMemsetAsync(d_ws, 0, 32768, stream);    // reset flags (graph-capture safe)

    void* args[] = {(void*)&xs, (void*)&Wi, (void*)&Wh, (void*)&b,
                    (void*)&Wo, (void*)&bo, (void*)&out, (void*)&hws,
                    (void*)&flags};
    hipLaunchCooperativeKernel((void*)lstm_fused, dim3(256), dim3(256), args, 0, stream);
}